// Round 4
// baseline (275.130 us; speedup 1.0000x reference)
//
#include <hip/hip_runtime.h>

// mean( (scale*(norms - label))^2 ), scale = 5 if label==1, 3 if label==2, else 1.
// B*S = 4096*8192 = 33,554,432 elements. Memory-bound streaming reduction.
// 268 MB traffic @ ~6.3 TB/s achievable -> ~43 us floor.

__device__ __forceinline__ float sq_term(float n, int l) {
    // scale*norms - scale*label = scale*(norms - label)
    float s = (l == 1) ? 5.0f : ((l == 2) ? 3.0f : 1.0f);
    float d = s * (n - (float)l);
    return d * d;
}

__global__ __launch_bounds__(256) void buff_loss_kernel(
        const float* __restrict__ norms,
        const int*   __restrict__ labs,
        float*       __restrict__ out,
        int nvec,            // number of float4/int4 groups
        float inv_n) {
    const float4* __restrict__ n4 = reinterpret_cast<const float4*>(norms);
    const int4*   __restrict__ l4 = reinterpret_cast<const int4*>(labs);

    float acc = 0.0f;
    const int tid    = blockIdx.x * blockDim.x + threadIdx.x;
    const int stride = gridDim.x * blockDim.x;

    // 2-way unrolled grid-stride: two independent 16B loads in flight per iter.
    int i = tid;
    for (; i + stride < nvec; i += 2 * stride) {
        float4 na = n4[i];
        int4   la = l4[i];
        float4 nb = n4[i + stride];
        int4   lb = l4[i + stride];
        acc += sq_term(na.x, la.x);
        acc += sq_term(na.y, la.y);
        acc += sq_term(na.z, la.z);
        acc += sq_term(na.w, la.w);
        acc += sq_term(nb.x, lb.x);
        acc += sq_term(nb.y, lb.y);
        acc += sq_term(nb.z, lb.z);
        acc += sq_term(nb.w, lb.w);
    }
    if (i < nvec) {
        float4 n = n4[i];
        int4   l = l4[i];
        acc += sq_term(n.x, l.x);
        acc += sq_term(n.y, l.y);
        acc += sq_term(n.z, l.z);
        acc += sq_term(n.w, l.w);
    }

    // wave64 shuffle reduction
    #pragma unroll
    for (int off = 32; off > 0; off >>= 1)
        acc += __shfl_down(acc, off, 64);

    __shared__ float smem[4];
    int lane = threadIdx.x & 63;
    int wid  = threadIdx.x >> 6;
    if (lane == 0) smem[wid] = acc;
    __syncthreads();

    if (threadIdx.x == 0) {
        float t = smem[0] + smem[1] + smem[2] + smem[3];
        atomicAdd(out, t * inv_n);
    }
}

extern "C" void kernel_launch(void* const* d_in, const int* in_sizes, int n_in,
                              void* d_out, int out_size, void* d_ws, size_t ws_size,
                              hipStream_t stream) {
    const float* norms = (const float*)d_in[0];
    const int*   labs  = (const int*)d_in[1];
    float*       out   = (float*)d_out;

    int n    = in_sizes[0];          // 33,554,432 (divisible by 4)
    int nvec = n >> 2;               // float4 groups
    float inv_n = 1.0f / (float)n;

    // d_out is re-poisoned to 0xAA before every timed call — zero it first.
    hipMemsetAsync(d_out, 0, sizeof(float), stream);

    const int block = 256;
    int grid = (nvec + block - 1) / block;
    if (grid > 2048) grid = 2048;

    buff_loss_kernel<<<grid, block, 0, stream>>>(norms, labs, out, nvec, inv_n);
}